// Round 7
// baseline (255.314 us; speedup 1.0000x reference)
//
#include <hip/hip_runtime.h>
#include <hip/hip_bf16.h>
#include <cmath>

// Problem constants
#define B_ 2
#define NQ_ 900
#define N_ 4096
#define LOG2E 1.4426950408889634f

typedef __attribute__((ext_vector_type(4))) float f32x4;
typedef __attribute__((ext_vector_type(8))) short s16x8;
typedef __attribute__((ext_vector_type(8))) _Float16 f16x8;
typedef __attribute__((ext_vector_type(4))) __fp16 h16x4;
typedef __attribute__((ext_vector_type(2))) __fp16 h16x2;

__device__ inline short f2bf(float x) {
    union { __hip_bfloat16 b; short s; } u;
    u.b = __float2bfloat16(x);
    return u.s;
}
__device__ inline short f2h(float x) {
    _Float16 h = (_Float16)x;
    return __builtin_bit_cast(short, h);
}

// ---------------------------------------------------------------------------
// Merged Q/K/V projection. V (mtx==2) emitted as f16 so attention's PV can
// use mfma_16x16x16 f16 with in-register P.
// ---------------------------------------------------------------------------
__global__ __launch_bounds__(256) void proj_kernel(
    const float* __restrict__ query, const float* __restrict__ kin,
    const float* __restrict__ vin,
    const float* __restrict__ Wq, const float* __restrict__ Wk,
    const float* __restrict__ Wv,
    const float* __restrict__ bqv, const float* __restrict__ bkv,
    const float* __restrict__ bvv,
    unsigned short* __restrict__ qbf, unsigned short* __restrict__ kbf,
    unsigned short* __restrict__ vbf, float qscale)
{
    const int mtx = blockIdx.z;
    const float* X = mtx == 0 ? query : mtx == 1 ? kin : vin;
    const float* W = mtx == 0 ? Wq : mtx == 1 ? Wk : Wv;
    const float* bias = mtx == 0 ? bqv : mtx == 1 ? bkv : bvv;
    unsigned short* Y = mtx == 0 ? qbf : mtx == 1 ? kbf : vbf;
    const int M = mtx == 0 ? 1800 : 8192;
    const int m0 = blockIdx.x * 64;
    if (m0 >= M) return;
    const float alpha = mtx == 0 ? qscale : 1.0f;
    const int rows_per_b = mtx == 0 ? 900 : 4096;
    const int ROWS = mtx == 0 ? 960 : 4096;

    __shared__ short Ab[16384];
    __shared__ short Bb[16384];
    const int tid = threadIdx.x;
    const int w = tid >> 6, l = tid & 63, quad = l >> 4, l15 = l & 15;
    const int wq = tid & 3, mm = tid >> 2;

    {
        const bool valid = (m0 + mm) < M;
        const float* xr = X + (size_t)(m0 + mm) * 256;
        #pragma unroll
        for (int it = 0; it < 8; ++it) {
            int g2 = it * 4 + wq;
            float4 a0 = make_float4(0.f, 0.f, 0.f, 0.f), a1 = a0;
            if (valid) {
                a0 = *(const float4*)(xr + g2 * 8);
                a1 = *(const float4*)(xr + g2 * 8 + 4);
            }
            uint4 pk;
            pk.x = (unsigned)(unsigned short)f2bf(a0.x) | ((unsigned)(unsigned short)f2bf(a0.y) << 16);
            pk.y = (unsigned)(unsigned short)f2bf(a0.z) | ((unsigned)(unsigned short)f2bf(a0.w) << 16);
            pk.z = (unsigned)(unsigned short)f2bf(a1.x) | ((unsigned)(unsigned short)f2bf(a1.y) << 16);
            pk.w = (unsigned)(unsigned short)f2bf(a1.z) | ((unsigned)(unsigned short)f2bf(a1.w) << 16);
            *(uint4*)(Ab + (it * 256 + mm * 4 + wq) * 8) = pk;
        }
    }

    for (int nt0 = 0; nt0 < 4; ++nt0) {
        const int n0 = nt0 * 64;
        {
            const float* wcol = W + n0 + mm;
            #pragma unroll
            for (int it = 0; it < 8; ++it) {
                int g2 = it * 4 + wq;
                uint4 wk4;
                wk4.x = (unsigned)(unsigned short)f2bf(wcol[(g2 * 8 + 0) * 256])
                      | ((unsigned)(unsigned short)f2bf(wcol[(g2 * 8 + 1) * 256]) << 16);
                wk4.y = (unsigned)(unsigned short)f2bf(wcol[(g2 * 8 + 2) * 256])
                      | ((unsigned)(unsigned short)f2bf(wcol[(g2 * 8 + 3) * 256]) << 16);
                wk4.z = (unsigned)(unsigned short)f2bf(wcol[(g2 * 8 + 4) * 256])
                      | ((unsigned)(unsigned short)f2bf(wcol[(g2 * 8 + 5) * 256]) << 16);
                wk4.w = (unsigned)(unsigned short)f2bf(wcol[(g2 * 8 + 6) * 256])
                      | ((unsigned)(unsigned short)f2bf(wcol[(g2 * 8 + 7) * 256]) << 16);
                *(uint4*)(Bb + (it * 256 + mm * 4 + wq) * 8) = wk4;
            }
        }
        __syncthreads();

        f32x4 acc[4] = {{0.f,0.f,0.f,0.f},{0.f,0.f,0.f,0.f},{0.f,0.f,0.f,0.f},{0.f,0.f,0.f,0.f}};
        #pragma unroll
        for (int kc = 0; kc < 8; ++kc) {
            s16x8 a = *(const s16x8*)(Ab + (kc * 256 + (w * 16 + l15) * 4 + quad) * 8);
            #pragma unroll
            for (int nt = 0; nt < 4; ++nt) {
                s16x8 bf = *(const s16x8*)(Bb + (kc * 256 + (nt * 16 + l15) * 4 + quad) * 8);
                acc[nt] = __builtin_amdgcn_mfma_f32_16x16x32_bf16(a, bf, acc[nt], 0, 0, 0);
            }
        }
        __syncthreads();

        #pragma unroll
        for (int nt = 0; nt < 4; ++nt) {
            int n = n0 + nt * 16 + l15;
            float bs = bias[n];
            int h = n >> 5, d = n & 31;
            #pragma unroll
            for (int r = 0; r < 4; ++r) {
                int row = m0 + w * 16 + quad * 4 + r;
                if (row < M) {
                    int b = row / rows_per_b;
                    int pos = row - b * rows_per_b;
                    float v = (acc[nt][r] + bs) * alpha;
                    Y[((size_t)(b * 8 + h) * ROWS + pos) * 32 + d] =
                        (unsigned short)(mtx == 2 ? f2h(v) : f2bf(v));
                }
            }
        }
    }
}

// ---------------------------------------------------------------------------
// Output projection via fp16 hi/lo split MFMA (unchanged).
// ---------------------------------------------------------------------------
__global__ __launch_bounds__(256) void outproj_kernel(
    const float* __restrict__ X, const float* __restrict__ W,
    const float* __restrict__ bias, float* __restrict__ Y, int M)
{
    __shared__ short Abh[4096], Abl[4096], Bbh[4096], Bbl[4096];
    const int tid = threadIdx.x;
    const int m0 = blockIdx.x * 64, n0 = blockIdx.y * 64;
    const int w = tid >> 6, l = tid & 63, quad = l >> 4, l15 = l & 15;
    const int wq = tid & 3, mm = tid >> 2;
    const bool valid = (m0 + mm) < M;
    const float* xr = X + (size_t)(m0 + mm) * 256;
    const float* wcol = W + n0 + mm;

    f32x4 acc[4] = {{0.f,0.f,0.f,0.f},{0.f,0.f,0.f,0.f},{0.f,0.f,0.f,0.f},{0.f,0.f,0.f,0.f}};

    for (int kq = 0; kq < 4; ++kq) {
        #pragma unroll
        for (int it = 0; it < 2; ++it) {
            int g2 = it * 4 + wq;
            int kbase = kq * 64 + g2 * 8;
            float av[8], bv[8];
            #pragma unroll
            for (int j = 0; j < 8; ++j) {
                av[j] = valid ? xr[kbase + j] : 0.f;
                bv[j] = wcol[(kbase + j) * 256];
            }
            uint4 ah, al, bh, bl;
            unsigned* ahp = (unsigned*)&ah; unsigned* alp = (unsigned*)&al;
            unsigned* bhp = (unsigned*)&bh; unsigned* blp = (unsigned*)&bl;
            #pragma unroll
            for (int j2 = 0; j2 < 4; ++j2) {
                _Float16 h0 = (_Float16)av[j2 * 2], h1 = (_Float16)av[j2 * 2 + 1];
                ahp[j2] = (unsigned)(unsigned short)__builtin_bit_cast(short, h0)
                        | ((unsigned)(unsigned short)__builtin_bit_cast(short, h1) << 16);
                alp[j2] = (unsigned)(unsigned short)f2h(av[j2 * 2] - (float)h0)
                        | ((unsigned)(unsigned short)f2h(av[j2 * 2 + 1] - (float)h1) << 16);
                _Float16 g0 = (_Float16)bv[j2 * 2], g1 = (_Float16)bv[j2 * 2 + 1];
                bhp[j2] = (unsigned)(unsigned short)__builtin_bit_cast(short, g0)
                        | ((unsigned)(unsigned short)__builtin_bit_cast(short, g1) << 16);
                blp[j2] = (unsigned)(unsigned short)f2h(bv[j2 * 2] - (float)g0)
                        | ((unsigned)(unsigned short)f2h(bv[j2 * 2 + 1] - (float)g1) << 16);
            }
            int gi = (it * 256 + mm * 4 + wq) * 8;
            *(uint4*)(Abh + gi) = ah;
            *(uint4*)(Abl + gi) = al;
            *(uint4*)(Bbh + gi) = bh;
            *(uint4*)(Bbl + gi) = bl;
        }
        __syncthreads();

        #pragma unroll
        for (int kc = 0; kc < 2; ++kc) {
            int ga = (kc * 256 + (w * 16 + l15) * 4 + quad) * 8;
            f16x8 ah = *(const f16x8*)(Abh + ga);
            f16x8 al = *(const f16x8*)(Abl + ga);
            #pragma unroll
            for (int nt = 0; nt < 4; ++nt) {
                int gb = (kc * 256 + (nt * 16 + l15) * 4 + quad) * 8;
                f16x8 bh = *(const f16x8*)(Bbh + gb);
                f16x8 bl = *(const f16x8*)(Bbl + gb);
                acc[nt] = __builtin_amdgcn_mfma_f32_16x16x32_f16(ah, bh, acc[nt], 0, 0, 0);
                acc[nt] = __builtin_amdgcn_mfma_f32_16x16x32_f16(ah, bl, acc[nt], 0, 0, 0);
                acc[nt] = __builtin_amdgcn_mfma_f32_16x16x32_f16(al, bh, acc[nt], 0, 0, 0);
            }
        }
        __syncthreads();
    }

    #pragma unroll
    for (int nt = 0; nt < 4; ++nt) {
        int n = n0 + nt * 16 + l15;
        float bs = bias[n];
        #pragma unroll
        for (int r = 0; r < 4; ++r) {
            int row = m0 + w * 16 + quad * 4 + r;
            if (row < M)
                Y[(size_t)row * 256 + n] = acc[nt][r] + bs;
        }
    }
}

// ---------------------------------------------------------------------------
// RPE v4 (unchanged): affine-in-pc layer-1, head-major output [h][q][pos].
// ---------------------------------------------------------------------------
__global__ __launch_bounds__(512) void rpe3_kernel(
    const float* __restrict__ ref2d,
    const float* __restrict__ W1x, const float* __restrict__ b1x,
    const float* __restrict__ W1y, const float* __restrict__ b1y,
    const float* __restrict__ W2x, const float* __restrict__ W2y,
    float* __restrict__ rpe_x, float* __restrict__ rpe_y)
{
    __shared__ short sw2h[8192], sw2l[8192];
    __shared__ float4 sUV[2 * 576];

    const int tid = threadIdx.x;
    for (int i = tid; i < 8192; i += 512) {
        int g = i >> 3, j = i & 7;
        int kcg = g >> 6, rr = g & 63, n = rr >> 2, q4 = rr & 3;
        int k = kcg * 32 + q4 * 8 + j;
        float val = ((n < 8) ? W2x[k * 8 + n] : W2y[k * 8 + (n - 8)]) * LOG2E;
        _Float16 hi = (_Float16)val;
        sw2h[i] = __builtin_bit_cast(short, hi);
        sw2l[i] = f2h(val - (float)hi);
    }
    {
        int k = tid;
        float w1x0 = W1x[k], w1x1 = W1x[512 + k];
        float w1y0 = W1y[k], w1y1 = W1y[512 + k];
        float bx = b1x[k], by = b1y[k];
        float vx = -(w1x0 + w1x1), vy = -(w1y0 + w1y1);
        #pragma unroll
        for (int q2 = 0; q2 < 2; ++q2) {
            const float4 bb = *(const float4*)(ref2d + (size_t)(blockIdx.x * 2 + q2) * 4);
            float ux = fmaf(w1x0, bb.x - bb.z * 0.5f, fmaf(w1x1, bb.x + bb.z * 0.5f, bx));
            float uy = fmaf(w1y0, bb.y - bb.w * 0.5f, fmaf(w1y1, bb.y + bb.w * 0.5f, by));
            sUV[q2 * 576 + (k >> 3) * 9 + (k & 7)] = make_float4(ux, vx, uy, vy);
        }
    }

    const int w = tid >> 6, l = tid & 63, quad = l >> 4, l15 = l & 15;
    const int qi = w >> 2, wrow = w & 3;
    const int bq = blockIdx.x * 2 + qi;
    const int row = wrow * 16 + l15;
    const float pc = (row + 0.5f) * 16.0f;

    __syncthreads();

    f32x4 accx = {0.f, 0.f, 0.f, 0.f}, accy = {0.f, 0.f, 0.f, 0.f};
    for (int kc = 0; kc < 16; ++kc) {
        f16x8 axh, axl, ayh, ayl;
        #pragma unroll
        for (int i = 0; i < 8; ++i) {
            float4 u = sUV[qi * 576 + (kc * 4 + quad) * 9 + i];
            float hx = fmaxf(fmaf(u.y, pc, u.x), 0.f);
            float hy = fmaxf(fmaf(u.w, pc, u.z), 0.f);
            _Float16 xh = (_Float16)hx;
            _Float16 yh = (_Float16)hy;
            axh[i] = xh;
            axl[i] = (_Float16)(hx - (float)xh);
            ayh[i] = yh;
            ayl[i] = (_Float16)(hy - (float)yh);
        }
        f16x8 bh = *(const f16x8*)(sw2h + (kc * 64 + l15 * 4 + quad) * 8);
        f16x8 bl = *(const f16x8*)(sw2l + (kc * 64 + l15 * 4 + quad) * 8);
        accx = __builtin_amdgcn_mfma_f32_16x16x32_f16(axh, bh, accx, 0, 0, 0);
        accx = __builtin_amdgcn_mfma_f32_16x16x32_f16(axh, bl, accx, 0, 0, 0);
        accx = __builtin_amdgcn_mfma_f32_16x16x32_f16(axl, bh, accx, 0, 0, 0);
        accy = __builtin_amdgcn_mfma_f32_16x16x32_f16(ayh, bh, accy, 0, 0, 0);
        accy = __builtin_amdgcn_mfma_f32_16x16x32_f16(ayh, bl, accy, 0, 0, 0);
        accy = __builtin_amdgcn_mfma_f32_16x16x32_f16(ayl, bh, accy, 0, 0, 0);
    }

    #pragma unroll
    for (int rr = 0; rr < 4; ++rr) {
        int row_out = wrow * 16 + quad * 4 + rr;
        if (l15 < 8) rpe_x[((size_t)l15 * 1800 + bq) * 64 + row_out] = accx[rr];
        else         rpe_y[((size_t)(l15 - 8) * 1800 + bq) * 64 + row_out] = accy[rr];
    }
}

// ---------------------------------------------------------------------------
// MFMA flash attention: SWAPPED QK^T (T12).
//  * launch_bounds (512,2): VGPR cap 256. (512,8)->cap32 spilled 930MB
//    (round 5); (512,4)+4-block LDS target -> alloc 64 + ~39MB loop spill
//    (round 6, WRITE_SIZE 42.9MB vs 4MB real). Let it keep the set resident.
//  * sc converted to f16 pa[t] right after exp2 (shorter live range).
// ---------------------------------------------------------------------------
__global__ __launch_bounds__(512, 2) void attn_mfma_kernel(
    const unsigned short* __restrict__ qb16, const unsigned short* __restrict__ kb16,
    const unsigned short* __restrict__ vb16,
    const float* __restrict__ rpe_x, const float* __restrict__ rpe_y,
    const unsigned char* __restrict__ mask, float* __restrict__ part)
{
    __shared__ short skf[4 * 2048];
    __shared__ short svt[4 * 2048];
    __shared__ float sry[32 * 33];              // [pos 32][q 32+pad]
    __shared__ unsigned long long smaskb[32];
    __shared__ float sm[8][16], sl[8][16], sMf[32], sLf[32];

    const int tid = threadIdx.x;
    const int qb = blockIdx.x, b = blockIdx.z;
    const int h = blockIdx.y & 7, kv = blockIdx.y >> 3;
    const int q0 = qb * 32;
    const int w = tid >> 6, l = tid & 63;
    const int qs = w >> 2, g = w & 3;
    const int quad = l >> 4, l15 = l & 15;

    const unsigned short* qg = qb16 + (size_t)(b * 8 + h) * 960 * 32;
    const unsigned short* kg = kb16 + (size_t)(b * 8 + h) * 4096 * 32 + (size_t)kv * 2048 * 32;
    const unsigned short* vg = vb16 + (size_t)(b * 8 + h) * 4096 * 32 + (size_t)kv * 2048 * 32;
    const float* rxh = rpe_x + ((size_t)h * 1800 + b * NQ_) * 64;
    const float* ryh = rpe_y + ((size_t)h * 1800 + b * NQ_) * 64;

    // stage rpe_y transposed: sry[pos][q] for this kv half
    for (int i = tid; i < 1024; i += 512) {
        int p = i & 31, ql = i >> 5;
        int qq = q0 + ql;
        float vy = (qq < NQ_) ? ryh[(size_t)qq * 64 + kv * 32 + p] : 0.f;
        sry[p * 33 + ql] = vy;
    }
    #pragma unroll
    for (int j = 0; j < 4; ++j) {
        int c = w * 4 + j;                       // local chunk 0..31
        unsigned long long bits = __ballot(mask[(size_t)b * N_ + (kv * 32 + c) * 64 + l] != 0);
        if (l == 0) smaskb[c] = bits;
    }

    // Q fragment (used as MFMA B operand after the swap)
    s16x8 qa = *(const s16x8*)(qg + (size_t)(q0 + qs * 16 + l15) * 32 + quad * 8);

    // rpe_x as C-init: rx4[t][r] = rpe_x[q = qs*16+l15][pos = t*16 + quad*4 + r]
    const int qq_l = q0 + qs * 16 + l15;
    f32x4 rx4[4];
    #pragma unroll
    for (int t = 0; t < 4; ++t)
        #pragma unroll
        for (int r = 0; r < 4; ++r)
            rx4[t][r] = (qq_l < NQ_) ? rxh[(size_t)qq_l * 64 + t * 16 + quad * 4 + r] : 0.f;

    const int sg = tid >> 7, role = (tid >> 6) & 1, stl = tid & 63;
    int eoff[4];
    if (role == 0) {
        #pragma unroll
        for (int t = 0; t < 4; ++t)
            eoff[t] = (t * 16 + (stl & 15)) * 32 + (stl >> 4) * 8;
    } else {
        #pragma unroll
        for (int t = 0; t < 4; ++t)
            eoff[t] = stl * 32 + t * 8;
    }
    const unsigned short* src = role ? vg : kg;

    uint4 pf[4];
    {
        size_t cb = (size_t)(sg * 8) * 2048;
        #pragma unroll
        for (int t = 0; t < 4; ++t) pf[t] = *(const uint4*)(src + cb + eoff[t]);
    }

    float mrow = -INFINITY;
    float lrow = 0.f;
    f32x4 acc0 = {0.f, 0.f, 0.f, 0.f}, acc1 = {0.f, 0.f, 0.f, 0.f};

    for (int i = 0; i < 8; ++i) {
        __syncthreads();
        if (role == 0) {
            #pragma unroll
            for (int t = 0; t < 4; ++t)
                *(uint4*)(skf + sg * 2048 + (t * 64 + stl) * 8) = pf[t];
        } else {
            short* vtw = svt + sg * 2048;
            #pragma unroll
            for (int t = 0; t < 4; ++t) {
                const unsigned short* pv = (const unsigned short*)&pf[t];
                #pragma unroll
                for (int j = 0; j < 8; ++j) {
                    int d = t * 8 + j;
                    vtw[d * 64 + (((stl >> 3) ^ (d & 7)) << 3) + (stl & 7)] = (short)pv[j];
                }
            }
        }
        __syncthreads();

        {
            int inext = (i + 1 < 8) ? i + 1 : 7;
            size_t cb = (size_t)(sg * 8 + inext) * 2048;
            #pragma unroll
            for (int t = 0; t < 4; ++t) pf[t] = *(const uint4*)(src + cb + eoff[t]);
        }

        const int lc = g * 8 + i;                // local chunk 0..31
        const short* kf = skf + g * 2048;

        // swapped QK^T: sc[t][r] = S[key = t*16+quad*4+r][q = qs*16+l15] (+rpe_x)
        f32x4 sc[4];
        #pragma unroll
        for (int t = 0; t < 4; ++t) {
            s16x8 kb = *(const s16x8*)(kf + (t * 64 + l) * 8);
            sc[t] = __builtin_amdgcn_mfma_f32_16x16x32_bf16(kb, qa, rx4[t], 0, 0, 0);
        }
        float ryv = sry[lc * 33 + qs * 16 + l15];  // scalar per lane (q = qs*16+l15)
        unsigned long long mb = smaskb[lc];
        if (mb) {
            unsigned long long mq = mb >> (quad * 4);
            #pragma unroll
            for (int t = 0; t < 4; ++t)
                #pragma unroll
                for (int r = 0; r < 4; ++r)
                    sc[t][r] += ((mq >> (t * 16 + r)) & 1ULL) ? -144.2695f : 0.f;
        }

        // per-lane chunk max over this quad's 16 keys
        float cmx = fmaxf(fmaxf(fmaxf(sc[0][0], sc[0][1]), fmaxf(sc[0][2], sc[0][3])),
                          fmaxf(fmaxf(sc[1][0], sc[1][1]), fmaxf(sc[1][2], sc[1][3])));
        cmx = fmaxf(cmx, fmaxf(fmaxf(fmaxf(sc[2][0], sc[2][1]), fmaxf(sc[2][2], sc[2][3])),
                               fmaxf(fmaxf(sc[3][0], sc[3][1]), fmaxf(sc[3][2], sc[3][3]))));
        cmx += ryv;

        // defer-max: slow path only when some lane's max exceeds mrow+8
        if (!__all(cmx <= mrow + 8.f)) {
            float cm = cmx;
            cm = fmaxf(cm, __shfl_xor(cm, 16));
            cm = fmaxf(cm, __shfl_xor(cm, 32));
            float mnew = fmaxf(mrow, cm);
            float al = exp2f(mrow - mnew);
            mrow = mnew;
            lrow *= al;
            #pragma unroll
            for (int r = 0; r < 4; ++r) { acc0[r] *= al; acc1[r] *= al; }
        }

        // exp2 + convert to f16 immediately (shortens sc live range)
        float msub = mrow - ryv;
        h16x4 pa[4];
        #pragma unroll
        for (int t = 0; t < 4; ++t) {
            float e0 = exp2f(sc[t][0] - msub);
            float e1 = exp2f(sc[t][1] - msub);
            float e2 = exp2f(sc[t][2] - msub);
            float e3 = exp2f(sc[t][3] - msub);
            lrow += (e0 + e1) + (e2 + e3);
            h16x2 p01 = __builtin_amdgcn_cvt_pkrtz(e0, e1);
            h16x2 p23 = __builtin_amdgcn_cvt_pkrtz(e2, e3);
            pa[t][0] = p01[0]; pa[t][1] = p01[1];
            pa[t][2] = p23[0]; pa[t][3] = p23[1];
        }

        // PV: in-register P (f16), V^T from svt; K=16 MFMA matches layout
        const short* vt = svt + g * 2048;
        #pragma unroll
        for (int t = 0; t < 4; ++t) {
            int pbase = (((t * 2 + (quad >> 1)) ^ (l15 & 7)) << 3) + ((quad & 1) << 2);
            h16x4 v0 = *(const h16x4*)(vt + l15 * 64 + pbase);
            h16x4 v1 = *(const h16x4*)(vt + (16 + l15) * 64 + pbase);
            acc0 = __builtin_amdgcn_mfma_f32_16x16x16f16(v0, pa[t], acc0, 0, 0, 0);
            acc1 = __builtin_amdgcn_mfma_f32_16x16x16f16(v1, pa[t], acc1, 0, 0, 0);
        }
    }

    // finish deferred cross-quad row sum (q = qs*16+l15)
    lrow += __shfl_xor(lrow, 16);
    lrow += __shfl_xor(lrow, 32);

    __syncthreads();
    if (quad == 0) {
        sm[w][l15] = mrow;
        sl[w][l15] = lrow;
    }
    __syncthreads();
    float mm = -INFINITY;
    #pragma unroll
    for (int gg = 0; gg < 4; ++gg) mm = fmaxf(mm, sm[qs * 4 + gg][l15]);
    float LL = 0.f;
    #pragma unroll
    for (int gg = 0; gg < 4; ++gg)
        LL += exp2f(sm[qs * 4 + gg][l15] - mm) * sl[qs * 4 + gg][l15];
    float wgt = exp2f(mrow - mm);
    if (g == 0 && quad == 0) {
        sMf[qs * 16 + l15] = mm;
        sLf[qs * 16 + l15] = LL;
    }

    // accumulate O across g-groups: obuf[q = qs*16+l15][dim]
    float* obuf = (float*)skf;
    for (int gg = 0; gg < 4; ++gg) {
        if (g == gg) {
            #pragma unroll
            for (int r = 0; r < 4; ++r) {
                int idx = (qs * 16 + l15) * 33 + quad * 4 + r;
                float v0 = wgt * acc0[r];
                float v1 = wgt * acc1[r];
                if (gg == 0) { obuf[idx] = v0; obuf[idx + 16] = v1; }
                else         { obuf[idx] += v0; obuf[idx + 16] += v1; }
            }
        }
        __syncthreads();
    }

    // write unnormalized partial (obuf 32x32, per-row M and L)
    float* po = part + (size_t)(((b * 8 + h) * 29 + qb) * 2 + kv) * 1088;
    for (int i = tid; i < 1024; i += 512)
        po[i] = obuf[(i >> 5) * 33 + (i & 31)];
    if (tid < 32) {
        po[1024 + tid] = sMf[tid];
        po[1056 + tid] = sLf[tid];
    }
}

// ---------------------------------------------------------------------------
// 2-way online-softmax merge of the split-K partials -> xws.
// ---------------------------------------------------------------------------
__global__ __launch_bounds__(256) void attn_merge_kernel(
    const float* __restrict__ part, float* __restrict__ xout)
{
    const int qb = blockIdx.x, h = blockIdx.y, b = blockIdx.z;
    const float* p0 = part + (size_t)(((b * 8 + h) * 29 + qb) * 2) * 1088;
    const float* p1 = p0 + 1088;
    __shared__ float a0s[32], a1s[32], iLs[32];
    const int tid = threadIdx.x;
    if (tid < 32) {
        float m0 = p0[1024 + tid], m1 = p1[1024 + tid];
        float M = fmaxf(m0, m1);
        float a0 = exp2f(m0 - M), a1 = exp2f(m1 - M);
        float L = a0 * p0[1056 + tid] + a1 * p1[1056 + tid];
        a0s[tid] = a0; a1s[tid] = a1; iLs[tid] = 1.0f / L;
    }
    __syncthreads();
    int i = tid * 4;                 // 256 threads x 4 floats = 1024
    int ql = i >> 5, d = i & 31;
    int qq = qb * 32 + ql;
    if (qq < NQ_) {
        const f32x4 v0 = *(const f32x4*)(p0 + i);
        const f32x4 v1 = *(const f32x4*)(p1 + i);
        float a0 = a0s[ql], a1 = a1s[ql], iL = iLs[ql];
        f32x4 o;
        #pragma unroll
        for (int j = 0; j < 4; ++j)
            o[j] = (a0 * v0[j] + a1 * v1[j]) * iL;
        *(f32x4*)(&xout[(size_t)(b * NQ_ + qq) * 256 + h * 32 + d]) = o;
    }
}

// ---------------------------------------------------------------------------
extern "C" void kernel_launch(void* const* d_in, const int* in_sizes, int n_in,
                              void* d_out, int out_size, void* d_ws, size_t ws_size,
                              hipStream_t stream)
{
    const float* query = (const float*)d_in[1];
    const float* ref2d = (const float*)d_in[2];
    const float* kin   = (const float*)d_in[3];
    const float* vin   = (const float*)d_in[4];
    const unsigned char* mask = (const unsigned char*)d_in[6];
    const float* W1x = (const float*)d_in[7];
    const float* b1x = (const float*)d_in[8];
    const float* W2x = (const float*)d_in[9];
    const float* W1y = (const float*)d_in[10];
    const float* b1y = (const float*)d_in[11];
    const float* W2y = (const float*)d_in[12];
    const float* Wq  = (const float*)d_in[13];
    const float* bq  = (const float*)d_in[14];
    const float* Wk  = (const float*)d_in[15];
    const float* bk  = (const float*)d_in[16];
    const float* Wv  = (const float*)d_in[17];
    const float* bv  = (const float*)d_in[18];
    const float* Wp  = (const float*)d_in[19];
    const float* bp  = (const float*)d_in[20];

    // Workspace ~22.6 MB (proven-safe footprint 27.8 MB)
    char* wsb = (char*)d_ws;
    unsigned short* qbf = (unsigned short*)(wsb);               //   983040 B
    unsigned short* kbf = (unsigned short*)(wsb +   983040);    //  4194304 B
    unsigned short* vbf = (unsigned short*)(wsb +  5177344);    //  4194304 B (f16)
    float* rxws = (float*)(wsb +  9371648);                     //  3686400 B
    float* ryws = (float*)(wsb + 13058048);                     //  3686400 B
    float* xws  = (float*)(wsb + 16744448);                     //  1843200 B
    float* part = (float*)(wsb + 18587648);                     //  4038656 B (928 x 1088 f32)
    float* out  = (float*)d_out;

    const float qscale = LOG2E / sqrtf(32.0f);   // exp2-domain softmax

    proj_kernel<<<dim3(128, 1, 3), 256, 0, stream>>>(
        query, kin, vin, Wq, Wk, Wv, bq, bk, bv, qbf, kbf, vbf, qscale);
    rpe3_kernel<<<900, 512, 0, stream>>>(
        ref2d, W1x, b1x, W1y, b1y, W2x, W2y, rxws, ryws);
    attn_mfma_kernel<<<dim3(29, 16, B_), 512, 0, stream>>>(
        qbf, kbf, vbf, rxws, ryws, mask, part);
    attn_merge_kernel<<<dim3(29, 8, B_), 256, 0, stream>>>(part, xws);
    outproj_kernel<<<dim3(29, 4), 256, 0, stream>>>(xws, Wp, bp, out, 1800);
}

// Round 8
// 232.107 us; speedup vs baseline: 1.1000x; 1.1000x over previous
//
#include <hip/hip_runtime.h>
#include <hip/hip_bf16.h>
#include <cmath>

// Problem constants
#define B_ 2
#define NQ_ 900
#define N_ 4096
#define LOG2E 1.4426950408889634f

typedef __attribute__((ext_vector_type(4))) float f32x4;
typedef __attribute__((ext_vector_type(8))) short s16x8;
typedef __attribute__((ext_vector_type(8))) _Float16 f16x8;

__device__ inline short f2bf(float x) {
    union { __hip_bfloat16 b; short s; } u;
    u.b = __float2bfloat16(x);
    return u.s;
}
__device__ inline short f2h(float x) {
    _Float16 h = (_Float16)x;
    return __builtin_bit_cast(short, h);
}

// DPP rotate within 16-lane row (VALU pipe; replaces ds_bpermute shuffles)
template <int CTRL>
__device__ inline float dppf(float x) {
    int xi = __builtin_bit_cast(int, x);
    int r = __builtin_amdgcn_update_dpp(xi, xi, CTRL, 0xF, 0xF, true);
    return __builtin_bit_cast(float, r);
}
__device__ inline float rowmax16(float v) {
    v = fmaxf(v, dppf<0x121>(v));
    v = fmaxf(v, dppf<0x122>(v));
    v = fmaxf(v, dppf<0x124>(v));
    v = fmaxf(v, dppf<0x128>(v));
    return v;
}
__device__ inline float rowsum16(float v) {
    v += dppf<0x121>(v);
    v += dppf<0x122>(v);
    v += dppf<0x124>(v);
    v += dppf<0x128>(v);
    return v;
}

// ---------------------------------------------------------------------------
// Merged Q/K/V projection. MFMA bf16, 64-row tile, K=256 LDS-resident A
// staged once; four 64-col n-tiles looped in-block.
// ---------------------------------------------------------------------------
__global__ __launch_bounds__(256) void proj_kernel(
    const float* __restrict__ query, const float* __restrict__ kin,
    const float* __restrict__ vin,
    const float* __restrict__ Wq, const float* __restrict__ Wk,
    const float* __restrict__ Wv,
    const float* __restrict__ bqv, const float* __restrict__ bkv,
    const float* __restrict__ bvv,
    unsigned short* __restrict__ qbf, unsigned short* __restrict__ kbf,
    unsigned short* __restrict__ vbf, float qscale)
{
    const int mtx = blockIdx.z;
    const float* X = mtx == 0 ? query : mtx == 1 ? kin : vin;
    const float* W = mtx == 0 ? Wq : mtx == 1 ? Wk : Wv;
    const float* bias = mtx == 0 ? bqv : mtx == 1 ? bkv : bvv;
    unsigned short* Y = mtx == 0 ? qbf : mtx == 1 ? kbf : vbf;
    const int M = mtx == 0 ? 1800 : 8192;
    const int m0 = blockIdx.x * 64;
    if (m0 >= M) return;
    const float alpha = mtx == 0 ? qscale : 1.0f;
    const int rows_per_b = mtx == 0 ? 900 : 4096;
    const int ROWS = mtx == 0 ? 960 : 4096;

    __shared__ short Ab[16384];
    __shared__ short Bb[16384];
    const int tid = threadIdx.x;
    const int w = tid >> 6, l = tid & 63, quad = l >> 4, l15 = l & 15;
    const int wq = tid & 3, mm = tid >> 2;

    {
        const bool valid = (m0 + mm) < M;
        const float* xr = X + (size_t)(m0 + mm) * 256;
        #pragma unroll
        for (int it = 0; it < 8; ++it) {
            int g2 = it * 4 + wq;
            float4 a0 = make_float4(0.f, 0.f, 0.f, 0.f), a1 = a0;
            if (valid) {
                a0 = *(const float4*)(xr + g2 * 8);
                a1 = *(const float4*)(xr + g2 * 8 + 4);
            }
            uint4 pk;
            pk.x = (unsigned)(unsigned short)f2bf(a0.x) | ((unsigned)(unsigned short)f2bf(a0.y) << 16);
            pk.y = (unsigned)(unsigned short)f2bf(a0.z) | ((unsigned)(unsigned short)f2bf(a0.w) << 16);
            pk.z = (unsigned)(unsigned short)f2bf(a1.x) | ((unsigned)(unsigned short)f2bf(a1.y) << 16);
            pk.w = (unsigned)(unsigned short)f2bf(a1.z) | ((unsigned)(unsigned short)f2bf(a1.w) << 16);
            *(uint4*)(Ab + (it * 256 + mm * 4 + wq) * 8) = pk;
        }
    }

    for (int nt0 = 0; nt0 < 4; ++nt0) {
        const int n0 = nt0 * 64;
        {
            const float* wcol = W + n0 + mm;
            #pragma unroll
            for (int it = 0; it < 8; ++it) {
                int g2 = it * 4 + wq;
                uint4 wk4;
                wk4.x = (unsigned)(unsigned short)f2bf(wcol[(g2 * 8 + 0) * 256])
                      | ((unsigned)(unsigned short)f2bf(wcol[(g2 * 8 + 1) * 256]) << 16);
                wk4.y = (unsigned)(unsigned short)f2bf(wcol[(g2 * 8 + 2) * 256])
                      | ((unsigned)(unsigned short)f2bf(wcol[(g2 * 8 + 3) * 256]) << 16);
                wk4.z = (unsigned)(unsigned short)f2bf(wcol[(g2 * 8 + 4) * 256])
                      | ((unsigned)(unsigned short)f2bf(wcol[(g2 * 8 + 5) * 256]) << 16);
                wk4.w = (unsigned)(unsigned short)f2bf(wcol[(g2 * 8 + 6) * 256])
                      | ((unsigned)(unsigned short)f2bf(wcol[(g2 * 8 + 7) * 256]) << 16);
                *(uint4*)(Bb + (it * 256 + mm * 4 + wq) * 8) = wk4;
            }
        }
        __syncthreads();

        f32x4 acc[4] = {{0.f,0.f,0.f,0.f},{0.f,0.f,0.f,0.f},{0.f,0.f,0.f,0.f},{0.f,0.f,0.f,0.f}};
        #pragma unroll
        for (int kc = 0; kc < 8; ++kc) {
            s16x8 a = *(const s16x8*)(Ab + (kc * 256 + (w * 16 + l15) * 4 + quad) * 8);
            #pragma unroll
            for (int nt = 0; nt < 4; ++nt) {
                s16x8 bf = *(const s16x8*)(Bb + (kc * 256 + (nt * 16 + l15) * 4 + quad) * 8);
                acc[nt] = __builtin_amdgcn_mfma_f32_16x16x32_bf16(a, bf, acc[nt], 0, 0, 0);
            }
        }
        __syncthreads();

        #pragma unroll
        for (int nt = 0; nt < 4; ++nt) {
            int n = n0 + nt * 16 + l15;
            float bs = bias[n];
            int h = n >> 5, d = n & 31;
            #pragma unroll
            for (int r = 0; r < 4; ++r) {
                int row = m0 + w * 16 + quad * 4 + r;
                if (row < M) {
                    int b = row / rows_per_b;
                    int pos = row - b * rows_per_b;
                    Y[((size_t)(b * 8 + h) * ROWS + pos) * 32 + d] =
                        (unsigned short)f2bf((acc[nt][r] + bs) * alpha);
                }
            }
        }
    }
}

// ---------------------------------------------------------------------------
// Output projection via fp16 hi/lo split MFMA.
// ---------------------------------------------------------------------------
__global__ __launch_bounds__(256) void outproj_kernel(
    const float* __restrict__ X, const float* __restrict__ W,
    const float* __restrict__ bias, float* __restrict__ Y, int M)
{
    __shared__ short Abh[4096], Abl[4096], Bbh[4096], Bbl[4096];
    const int tid = threadIdx.x;
    const int m0 = blockIdx.x * 64, n0 = blockIdx.y * 64;
    const int w = tid >> 6, l = tid & 63, quad = l >> 4, l15 = l & 15;
    const int wq = tid & 3, mm = tid >> 2;
    const bool valid = (m0 + mm) < M;
    const float* xr = X + (size_t)(m0 + mm) * 256;
    const float* wcol = W + n0 + mm;

    f32x4 acc[4] = {{0.f,0.f,0.f,0.f},{0.f,0.f,0.f,0.f},{0.f,0.f,0.f,0.f},{0.f,0.f,0.f,0.f}};

    for (int kq = 0; kq < 4; ++kq) {
        #pragma unroll
        for (int it = 0; it < 2; ++it) {
            int g2 = it * 4 + wq;
            int kbase = kq * 64 + g2 * 8;
            float av[8], bv[8];
            #pragma unroll
            for (int j = 0; j < 8; ++j) {
                av[j] = valid ? xr[kbase + j] : 0.f;
                bv[j] = wcol[(kbase + j) * 256];
            }
            uint4 ah, al, bh, bl;
            unsigned* ahp = (unsigned*)&ah; unsigned* alp = (unsigned*)&al;
            unsigned* bhp = (unsigned*)&bh; unsigned* blp = (unsigned*)&bl;
            #pragma unroll
            for (int j2 = 0; j2 < 4; ++j2) {
                _Float16 h0 = (_Float16)av[j2 * 2], h1 = (_Float16)av[j2 * 2 + 1];
                ahp[j2] = (unsigned)(unsigned short)__builtin_bit_cast(short, h0)
                        | ((unsigned)(unsigned short)__builtin_bit_cast(short, h1) << 16);
                alp[j2] = (unsigned)(unsigned short)f2h(av[j2 * 2] - (float)h0)
                        | ((unsigned)(unsigned short)f2h(av[j2 * 2 + 1] - (float)h1) << 16);
                _Float16 g0 = (_Float16)bv[j2 * 2], g1 = (_Float16)bv[j2 * 2 + 1];
                bhp[j2] = (unsigned)(unsigned short)__builtin_bit_cast(short, g0)
                        | ((unsigned)(unsigned short)__builtin_bit_cast(short, g1) << 16);
                blp[j2] = (unsigned)(unsigned short)f2h(bv[j2 * 2] - (float)g0)
                        | ((unsigned)(unsigned short)f2h(bv[j2 * 2 + 1] - (float)g1) << 16);
            }
            int gi = (it * 256 + mm * 4 + wq) * 8;
            *(uint4*)(Abh + gi) = ah;
            *(uint4*)(Abl + gi) = al;
            *(uint4*)(Bbh + gi) = bh;
            *(uint4*)(Bbl + gi) = bl;
        }
        __syncthreads();

        #pragma unroll
        for (int kc = 0; kc < 2; ++kc) {
            int ga = (kc * 256 + (w * 16 + l15) * 4 + quad) * 8;
            f16x8 ah = *(const f16x8*)(Abh + ga);
            f16x8 al = *(const f16x8*)(Abl + ga);
            #pragma unroll
            for (int nt = 0; nt < 4; ++nt) {
                int gb = (kc * 256 + (nt * 16 + l15) * 4 + quad) * 8;
                f16x8 bh = *(const f16x8*)(Bbh + gb);
                f16x8 bl = *(const f16x8*)(Bbl + gb);
                acc[nt] = __builtin_amdgcn_mfma_f32_16x16x32_f16(ah, bh, acc[nt], 0, 0, 0);
                acc[nt] = __builtin_amdgcn_mfma_f32_16x16x32_f16(ah, bl, acc[nt], 0, 0, 0);
                acc[nt] = __builtin_amdgcn_mfma_f32_16x16x32_f16(al, bh, acc[nt], 0, 0, 0);
            }
        }
        __syncthreads();
    }

    #pragma unroll
    for (int nt = 0; nt < 4; ++nt) {
        int n = n0 + nt * 16 + l15;
        float bs = bias[n];
        #pragma unroll
        for (int r = 0; r < 4; ++r) {
            int row = m0 + w * 16 + quad * 4 + r;
            if (row < M)
                Y[(size_t)row * 256 + n] = acc[nt][r] + bs;
        }
    }
}

// ---------------------------------------------------------------------------
// RPE v4: affine-in-pc layer-1 (u_k per query, v_k constant), head-major
// output [h][q][pos] so attn reads are fully coalesced.
// ---------------------------------------------------------------------------
__global__ __launch_bounds__(512) void rpe3_kernel(
    const float* __restrict__ ref2d,
    const float* __restrict__ W1x, const float* __restrict__ b1x,
    const float* __restrict__ W1y, const float* __restrict__ b1y,
    const float* __restrict__ W2x, const float* __restrict__ W2y,
    float* __restrict__ rpe_x, float* __restrict__ rpe_y)
{
    __shared__ short sw2h[8192], sw2l[8192];
    __shared__ float4 sUV[2 * 576];

    const int tid = threadIdx.x;
    for (int i = tid; i < 8192; i += 512) {
        int g = i >> 3, j = i & 7;
        int kcg = g >> 6, rr = g & 63, n = rr >> 2, q4 = rr & 3;
        int k = kcg * 32 + q4 * 8 + j;
        float val = ((n < 8) ? W2x[k * 8 + n] : W2y[k * 8 + (n - 8)]) * LOG2E;
        _Float16 hi = (_Float16)val;
        sw2h[i] = __builtin_bit_cast(short, hi);
        sw2l[i] = f2h(val - (float)hi);
    }
    {
        int k = tid;
        float w1x0 = W1x[k], w1x1 = W1x[512 + k];
        float w1y0 = W1y[k], w1y1 = W1y[512 + k];
        float bx = b1x[k], by = b1y[k];
        float vx = -(w1x0 + w1x1), vy = -(w1y0 + w1y1);
        #pragma unroll
        for (int q2 = 0; q2 < 2; ++q2) {
            const float4 bb = *(const float4*)(ref2d + (size_t)(blockIdx.x * 2 + q2) * 4);
            float ux = fmaf(w1x0, bb.x - bb.z * 0.5f, fmaf(w1x1, bb.x + bb.z * 0.5f, bx));
            float uy = fmaf(w1y0, bb.y - bb.w * 0.5f, fmaf(w1y1, bb.y + bb.w * 0.5f, by));
            sUV[q2 * 576 + (k >> 3) * 9 + (k & 7)] = make_float4(ux, vx, uy, vy);
        }
    }

    const int w = tid >> 6, l = tid & 63, quad = l >> 4, l15 = l & 15;
    const int qi = w >> 2, wrow = w & 3;
    const int bq = blockIdx.x * 2 + qi;
    const int row = wrow * 16 + l15;
    const float pc = (row + 0.5f) * 16.0f;

    __syncthreads();

    f32x4 accx = {0.f, 0.f, 0.f, 0.f}, accy = {0.f, 0.f, 0.f, 0.f};
    for (int kc = 0; kc < 16; ++kc) {
        f16x8 axh, axl, ayh, ayl;
        #pragma unroll
        for (int i = 0; i < 8; ++i) {
            float4 u = sUV[qi * 576 + (kc * 4 + quad) * 9 + i];
            float hx = fmaxf(fmaf(u.y, pc, u.x), 0.f);
            float hy = fmaxf(fmaf(u.w, pc, u.z), 0.f);
            _Float16 xh = (_Float16)hx;
            _Float16 yh = (_Float16)hy;
            axh[i] = xh;
            axl[i] = (_Float16)(hx - (float)xh);
            ayh[i] = yh;
            ayl[i] = (_Float16)(hy - (float)yh);
        }
        f16x8 bh = *(const f16x8*)(sw2h + (kc * 64 + l15 * 4 + quad) * 8);
        f16x8 bl = *(const f16x8*)(sw2l + (kc * 64 + l15 * 4 + quad) * 8);
        accx = __builtin_amdgcn_mfma_f32_16x16x32_f16(axh, bh, accx, 0, 0, 0);
        accx = __builtin_amdgcn_mfma_f32_16x16x32_f16(axh, bl, accx, 0, 0, 0);
        accx = __builtin_amdgcn_mfma_f32_16x16x32_f16(axl, bh, accx, 0, 0, 0);
        accy = __builtin_amdgcn_mfma_f32_16x16x32_f16(ayh, bh, accy, 0, 0, 0);
        accy = __builtin_amdgcn_mfma_f32_16x16x32_f16(ayh, bl, accy, 0, 0, 0);
        accy = __builtin_amdgcn_mfma_f32_16x16x32_f16(ayl, bh, accy, 0, 0, 0);
    }

    #pragma unroll
    for (int rr = 0; rr < 4; ++rr) {
        int row_out = wrow * 16 + quad * 4 + rr;
        if (l15 < 8) rpe_x[((size_t)l15 * 1800 + bq) * 64 + row_out] = accx[rr];
        else         rpe_y[((size_t)(l15 - 8) * 1800 + bq) * 64 + row_out] = accy[rr];
    }
}

// ---------------------------------------------------------------------------
// MFMA flash attention (round-1 verified config: full-K per block, defer-max
// + defer-sum DPP softmax, head-major rpe reads, P via swizzled spb LDS,
// bf16 PV). Rounds 2-7 established: split-K neutral; swapped-QK^T (T12)
// regressed (V^T scatter staging + per-lane mask cost > softmax savings);
// (512,8)/(512,2) launch-bounds both regressed via spill / lost occupancy.
// ---------------------------------------------------------------------------
__global__ __launch_bounds__(512, 4) void attn_mfma_kernel(
    const unsigned short* __restrict__ qb16, const unsigned short* __restrict__ kb16,
    const unsigned short* __restrict__ vb16,
    const float* __restrict__ rpe_x, const float* __restrict__ rpe_y,
    const unsigned char* __restrict__ mask, float* __restrict__ xout)
{
    __shared__ short skf[4 * 2048];
    __shared__ short svt[4 * 2048];
    __shared__ short spb[8 * 544];
    __shared__ float ry[32 * 65];
    __shared__ unsigned long long smaskb[64];
    __shared__ float sm[8][16], sl[8][16], sLf[32];

    const int tid = threadIdx.x;
    const int qb = blockIdx.x, h = blockIdx.y, b = blockIdx.z;
    const int q0 = qb * 32;
    const int w = tid >> 6, l = tid & 63;
    const int qsub = w >> 2, g = w & 3;
    const int quad = l >> 4, l15 = l & 15;

    const unsigned short* qg = qb16 + (size_t)(b * 8 + h) * 960 * 32;
    const unsigned short* kg = kb16 + (size_t)(b * 8 + h) * 4096 * 32;
    const unsigned short* vg = vb16 + (size_t)(b * 8 + h) * 4096 * 32;
    const float* rxh = rpe_x + ((size_t)h * 1800 + b * NQ_) * 64;
    const float* ryh = rpe_y + ((size_t)h * 1800 + b * NQ_) * 64;

    for (int i = tid; i < 2048; i += 512) {
        int qq = q0 + (i >> 6), pos = i & 63;
        float vy = 0.f;
        if (qq < NQ_)
            vy = ryh[(size_t)qq * 64 + pos];
        ry[(i >> 6) * 65 + pos] = vy;
    }
    #pragma unroll
    for (int j = 0; j < 8; ++j) {
        int c = w * 8 + j;
        unsigned long long bits = __ballot(mask[(size_t)b * N_ + c * 64 + l] != 0);
        if (l == 0) smaskb[c] = bits;
    }

    s16x8 qa = *(const s16x8*)(qg + (size_t)(q0 + qsub * 16 + l15) * 32 + quad * 8);

    f32x4 rx4[4];
    #pragma unroll
    for (int t = 0; t < 4; ++t)
        #pragma unroll
        for (int r = 0; r < 4; ++r) {
            int qq = q0 + qsub * 16 + quad * 4 + r;
            rx4[t][r] = (qq < NQ_) ? rxh[(size_t)qq * 64 + t * 16 + l15] : 0.f;
        }

    const int sg = tid >> 7, role = (tid >> 6) & 1, stl = tid & 63;
    int eoff[4];
    if (role == 0) {
        #pragma unroll
        for (int t = 0; t < 4; ++t)
            eoff[t] = (t * 16 + (stl & 15)) * 32 + (stl >> 4) * 8;
    } else {
        #pragma unroll
        for (int t = 0; t < 4; ++t)
            eoff[t] = stl * 32 + t * 8;
    }
    const unsigned short* src = role ? vg : kg;

    uint4 pf[4];
    {
        size_t cb = (size_t)(sg * 16) * 2048;
        #pragma unroll
        for (int t = 0; t < 4; ++t) pf[t] = *(const uint4*)(src + cb + eoff[t]);
    }

    float mrow[4] = {-INFINITY, -INFINITY, -INFINITY, -INFINITY};
    float lrow[4] = {0.f, 0.f, 0.f, 0.f};
    f32x4 acc0 = {0.f, 0.f, 0.f, 0.f}, acc1 = {0.f, 0.f, 0.f, 0.f};
    short* pw = spb + w * 544;

    for (int i = 0; i < 16; ++i) {
        __syncthreads();
        if (role == 0) {
            #pragma unroll
            for (int t = 0; t < 4; ++t)
                *(uint4*)(skf + sg * 2048 + (t * 64 + stl) * 8) = pf[t];
        } else {
            short* vtw = svt + sg * 2048;
            #pragma unroll
            for (int t = 0; t < 4; ++t) {
                const unsigned short* pv = (const unsigned short*)&pf[t];
                #pragma unroll
                for (int j = 0; j < 8; ++j) {
                    int d = t * 8 + j;
                    vtw[d * 64 + (((stl >> 3) ^ (d & 7)) << 3) + (stl & 7)] = (short)pv[j];
                }
            }
        }
        __syncthreads();

        {
            int inext = (i + 1 < 16) ? i + 1 : 15;
            size_t cb = (size_t)(sg * 16 + inext) * 2048;
            #pragma unroll
            for (int t = 0; t < 4; ++t) pf[t] = *(const uint4*)(src + cb + eoff[t]);
        }

        const int cgc = g * 16 + i;
        const short* kf = skf + g * 2048;

        f32x4 sc[4];
        #pragma unroll
        for (int t = 0; t < 4; ++t) {
            s16x8 kb = *(const s16x8*)(kf + (t * 64 + l) * 8);
            sc[t] = __builtin_amdgcn_mfma_f32_16x16x32_bf16(qa, kb, rx4[t], 0, 0, 0);
        }
        float ryv[4];
        #pragma unroll
        for (int r = 0; r < 4; ++r)
            ryv[r] = ry[(qsub * 16 + quad * 4 + r) * 65 + cgc];
        unsigned long long mb = smaskb[cgc];
        if (mb) {
            #pragma unroll
            for (int t = 0; t < 4; ++t) {
                float mk = ((mb >> (t * 16 + l15)) & 1ULL) ? -144.2695f : 0.f;
                #pragma unroll
                for (int r = 0; r < 4; ++r) sc[t][r] += mk;
            }
        }

        // chunk max (per-lane partial over this lane's 4 columns), incl. ry
        float cmr[4];
        #pragma unroll
        for (int r = 0; r < 4; ++r)
            cmr[r] = fmaxf(fmaxf(sc[0][r], sc[1][r]), fmaxf(sc[2][r], sc[3][r])) + ryv[r];

        // defer-max: only run the DPP rowmax + rescale when some lane's
        // chunk max could exceed mrow by >8 (exp2-domain; P <= 2^8).
        int ok = (cmr[0] <= mrow[0] + 8.f) & (cmr[1] <= mrow[1] + 8.f)
               & (cmr[2] <= mrow[2] + 8.f) & (cmr[3] <= mrow[3] + 8.f);
        if (!__all(ok)) {
            #pragma unroll
            for (int r = 0; r < 4; ++r) {
                float cm = rowmax16(cmr[r]);
                float mnew = fmaxf(mrow[r], cm);
                float al = exp2f(mrow[r] - mnew);
                mrow[r] = mnew;
                lrow[r] *= al;
                acc0[r] *= al;
                acc1[r] *= al;
            }
        }

        float msub[4];
        #pragma unroll
        for (int r = 0; r < 4; ++r) msub[r] = mrow[r] - ryv[r];
        #pragma unroll
        for (int t = 0; t < 4; ++t)
            #pragma unroll
            for (int r = 0; r < 4; ++r)
                sc[t][r] = exp2f(sc[t][r] - msub[r]);
        // defer-sum: per-lane partial only; cross-lane rowsum16 once at end
        #pragma unroll
        for (int r = 0; r < 4; ++r)
            lrow[r] += (sc[0][r] + sc[1][r]) + (sc[2][r] + sc[3][r]);

        const short* vt = svt + g * 2048;
        #pragma unroll
        for (int hh = 0; hh < 2; ++hh) {
            #pragma unroll
            for (int tt = 0; tt < 2; ++tt) {
                int t = hh * 2 + tt;
                int gphys = (tt * 2 + (l15 >> 3)) ^ quad;
                #pragma unroll
                for (int r = 0; r < 4; ++r)
                    pw[(gphys * 17 + quad * 4 + r) * 8 + (l15 & 7)] = f2bf(sc[t][r]);
            }
            int gph_r = quad ^ (l15 >> 2);
            s16x8 pa  = *(const s16x8*)(pw + (gph_r * 17 + l15) * 8);
            int ksw = ((hh * 4 + quad) ^ (l15 & 7)) * 8;
            s16x8 vb0 = *(const s16x8*)(vt + l15 * 64 + ksw);
            s16x8 vb1 = *(const s16x8*)(vt + (16 + l15) * 64 + ksw);
            acc0 = __builtin_amdgcn_mfma_f32_16x16x32_bf16(pa, vb0, acc0, 0, 0, 0);
            acc1 = __builtin_amdgcn_mfma_f32_16x16x32_bf16(pa, vb1, acc1, 0, 0, 0);
        }
    }

    // finish the deferred cross-lane row sum (was per-iteration)
    #pragma unroll
    for (int r = 0; r < 4; ++r) lrow[r] = rowsum16(lrow[r]);

    __syncthreads();
    if (l15 == 0) {
        #pragma unroll
        for (int r = 0; r < 4; ++r) {
            sm[w][quad * 4 + r] = mrow[r];
            sl[w][quad * 4 + r] = lrow[r];
        }
    }
    __syncthreads();
    float wgt[4], L4[4];
    #pragma unroll
    for (int r = 0; r < 4; ++r) {
        int qrow = quad * 4 + r;
        float mm = -INFINITY;
        #pragma unroll
        for (int gg = 0; gg < 4; ++gg) mm = fmaxf(mm, sm[qsub * 4 + gg][qrow]);
        float LL = 0.f;
        #pragma unroll
        for (int gg = 0; gg < 4; ++gg)
            LL += exp2f(sm[qsub * 4 + gg][qrow] - mm) * sl[qsub * 4 + gg][qrow];
        wgt[r] = exp2f(mrow[r] - mm);
        L4[r] = LL;
    }
    if (g == 0 && l15 == 0) {
        #pragma unroll
        for (int r = 0; r < 4; ++r) sLf[qsub * 16 + quad * 4 + r] = L4[r];
    }

    float* obuf = (float*)skf;
    for (int gg = 0; gg < 4; ++gg) {
        if (g == gg) {
            #pragma unroll
            for (int r = 0; r < 4; ++r) {
                int idx = (qsub * 16 + quad * 4 + r) * 33 + l15;
                float v0 = wgt[r] * acc0[r];
                float v1 = wgt[r] * acc1[r];
                if (gg == 0) { obuf[idx] = v0; obuf[idx + 16] = v1; }
                else         { obuf[idx] += v0; obuf[idx + 16] += v1; }
            }
        }
        __syncthreads();
    }

    for (int i = tid; i < 1024; i += 512) {
        int ql = i >> 5, d = i & 31;
        int qq = q0 + ql;
        if (qq < NQ_)
            xout[(size_t)(b * NQ_ + qq) * 256 + h * 32 + d] = obuf[ql * 33 + d] / sLf[ql];
    }
}

// ---------------------------------------------------------------------------
extern "C" void kernel_launch(void* const* d_in, const int* in_sizes, int n_in,
                              void* d_out, int out_size, void* d_ws, size_t ws_size,
                              hipStream_t stream)
{
    const float* query = (const float*)d_in[1];
    const float* ref2d = (const float*)d_in[2];
    const float* kin   = (const float*)d_in[3];
    const float* vin   = (const float*)d_in[4];
    const unsigned char* mask = (const unsigned char*)d_in[6];
    const float* W1x = (const float*)d_in[7];
    const float* b1x = (const float*)d_in[8];
    const float* W2x = (const float*)d_in[9];
    const float* W1y = (const float*)d_in[10];
    const float* b1y = (const float*)d_in[11];
    const float* W2y = (const float*)d_in[12];
    const float* Wq  = (const float*)d_in[13];
    const float* bq  = (const float*)d_in[14];
    const float* Wk  = (const float*)d_in[15];
    const float* bk  = (const float*)d_in[16];
    const float* Wv  = (const float*)d_in[17];
    const float* bv  = (const float*)d_in[18];
    const float* Wp  = (const float*)d_in[19];
    const float* bp  = (const float*)d_in[20];

    // Workspace ~18.6 MB (proven-safe footprint 27.8 MB)
    char* wsb = (char*)d_ws;
    unsigned short* qbf = (unsigned short*)(wsb);               //   983040 B
    unsigned short* kbf = (unsigned short*)(wsb +   983040);    //  4194304 B
    unsigned short* vbf = (unsigned short*)(wsb +  5177344);    //  4194304 B
    float* rxws = (float*)(wsb +  9371648);                     //  3686400 B
    float* ryws = (float*)(wsb + 13058048);                     //  3686400 B
    float* xws  = (float*)(wsb + 16744448);                     //  1843200 B
    float* out  = (float*)d_out;

    const float qscale = LOG2E / sqrtf(32.0f);   // exp2-domain softmax

    proj_kernel<<<dim3(128, 1, 3), 256, 0, stream>>>(
        query, kin, vin, Wq, Wk, Wv, bq, bk, bv, qbf, kbf, vbf, qscale);
    rpe3_kernel<<<900, 512, 0, stream>>>(
        ref2d, W1x, b1x, W1y, b1y, W2x, W2y, rxws, ryws);
    attn_mfma_kernel<<<dim3(29, 8, B_), 512, 0, stream>>>(
        qbf, kbf, vbf, rxws, ryws, mask, xws);
    outproj_kernel<<<dim3(29, 4), 256, 0, stream>>>(xws, Wp, bp, out, 1800);
}